// Round 3
// baseline (1258.836 us; speedup 1.0000x reference)
//
#include <hip/hip_runtime.h>
#include <hip/hip_bf16.h>

typedef __attribute__((ext_vector_type(8))) short short8;
typedef __attribute__((ext_vector_type(4))) float f32x4;

__device__ __forceinline__ short f2bfbits(float f) {
  union { __hip_bfloat16 h; short s; } cvt;
  cvt.h = __float2bfloat16(f);
  return cvt.s;
}
__device__ __forceinline__ float bfbits2f(short bits) {
  union { unsigned int u; float f; } cvt;
  cvt.u = ((unsigned int)(unsigned short)bits) << 16;
  return cvt.f;
}

// ---------------- fp32 -> bf16 weight conversion (once per launch) ----------
__global__ __launch_bounds__(256)
void f2bf(const float* __restrict__ s, short* __restrict__ d, int n) {
  const int i = (blockIdx.x * 256 + threadIdx.x) * 4;
  if (i >= n) return;
  float4 v = *(const float4*)(s + i);
  short o[4] = {f2bfbits(v.x), f2bfbits(v.y), f2bfbits(v.z), f2bfbits(v.w)};
  *(uint2*)(d + i) = *(const uint2*)o;
}

// ---------------- LN1 + roll(-4,-4) + window partition (fp32 in, bf16 out) --
// dst token t (window layout: b*4096 + wi*64 + n). One wave per token.
__global__ __launch_bounds__(256)
void ln1_win(const float* __restrict__ x, const float* __restrict__ w,
             const float* __restrict__ b, short* __restrict__ h) {
  const int lane = threadIdx.x & 63;
  const int wv = threadIdx.x >> 6;
  const int t = blockIdx.x * 4 + wv;
  const int n = t & 63, wiB = t >> 6;
  const int wi = wiB & 63, bb = wiB >> 6;
  const int sr = (((wi >> 3) << 3) + (n >> 3) + 4) & 63;
  const int sc = (((wi & 7) << 3) + (n & 7) + 4) & 63;
  const float* xp = x + ((long)bb * 4096 + sr * 64 + sc) * 512 + lane * 8;
  float4 u0 = *(const float4*)(xp);
  float4 u1 = *(const float4*)(xp + 4);
  float v[8] = {u0.x, u0.y, u0.z, u0.w, u1.x, u1.y, u1.z, u1.w};
  float s = 0.f;
#pragma unroll
  for (int j = 0; j < 8; j++) s += v[j];
#pragma unroll
  for (int o = 1; o < 64; o <<= 1) s += __shfl_xor(s, o, 64);
  const float mean = s * (1.0f / 512.0f);
  float q = 0.f;
#pragma unroll
  for (int j = 0; j < 8; j++) { float d = v[j] - mean; q += d * d; }
#pragma unroll
  for (int o = 1; o < 64; o <<= 1) q += __shfl_xor(q, o, 64);
  const float rstd = rsqrtf(q * (1.0f / 512.0f) + 1e-5f);
  float4 w0 = *(const float4*)(w + lane * 8);
  float4 w1 = *(const float4*)(w + lane * 8 + 4);
  float4 b0 = *(const float4*)(b + lane * 8);
  float4 b1 = *(const float4*)(b + lane * 8 + 4);
  const float wv8[8] = {w0.x, w0.y, w0.z, w0.w, w1.x, w1.y, w1.z, w1.w};
  const float bv8[8] = {b0.x, b0.y, b0.z, b0.w, b1.x, b1.y, b1.z, b1.w};
  short outs[8];
#pragma unroll
  for (int j = 0; j < 8; j++)
    outs[j] = f2bfbits((v[j] - mean) * rstd * wv8[j] + bv8[j]);
  *(uint4*)(h + (long)t * 512 + lane * 8) = *(const uint4*)outs;
}

// ---------------- LN2 (identity layout, fp32 in, bf16 out) ----------------
__global__ __launch_bounds__(256)
void ln2_id(const float* __restrict__ x2, const float* __restrict__ w,
            const float* __restrict__ b, short* __restrict__ out) {
  const int lane = threadIdx.x & 63;
  const int wv = threadIdx.x >> 6;
  const long t = blockIdx.x * 4 + wv;
  const float* xp = x2 + t * 512 + lane * 8;
  float4 u0 = *(const float4*)(xp);
  float4 u1 = *(const float4*)(xp + 4);
  float v[8] = {u0.x, u0.y, u0.z, u0.w, u1.x, u1.y, u1.z, u1.w};
  float s = 0.f;
#pragma unroll
  for (int j = 0; j < 8; j++) s += v[j];
#pragma unroll
  for (int o = 1; o < 64; o <<= 1) s += __shfl_xor(s, o, 64);
  const float mean = s * (1.0f / 512.0f);
  float q = 0.f;
#pragma unroll
  for (int j = 0; j < 8; j++) { float d = v[j] - mean; q += d * d; }
#pragma unroll
  for (int o = 1; o < 64; o <<= 1) q += __shfl_xor(q, o, 64);
  const float rstd = rsqrtf(q * (1.0f / 512.0f) + 1e-5f);
  float4 w0 = *(const float4*)(w + lane * 8);
  float4 w1 = *(const float4*)(w + lane * 8 + 4);
  float4 b0 = *(const float4*)(b + lane * 8);
  float4 b1 = *(const float4*)(b + lane * 8 + 4);
  const float wv8[8] = {w0.x, w0.y, w0.z, w0.w, w1.x, w1.y, w1.z, w1.w};
  const float bv8[8] = {b0.x, b0.y, b0.z, b0.w, b1.x, b1.y, b1.z, b1.w};
  short outs[8];
#pragma unroll
  for (int j = 0; j < 8; j++)
    outs[j] = f2bfbits((v[j] - mean) * rstd * wv8[j] + bv8[j]);
  *(uint4*)(out + t * 512 + lane * 8) = *(const uint4*)outs;
}

// ---------------- Generic B^T GEMM: out[M,N] = A[M,K] @ Bw[N,K]^T + epilogue ----
// A, Bw are bf16; bias/aux fp32.
// MODE 0: +bias -> bf16 store (qkv)
// MODE 1: +bias, window-reverse + roll(+4) scatter, + residual aux (fp32) -> fp32 store
// MODE 2: +bias, exact GELU -> bf16 store (fc1)
// MODE 3: +bias, + residual aux (fp32, row-major) -> fp32 store (fc2 / final out)
template <int MODE, int K, int N>
__global__ __launch_bounds__(256)
void gemm_bt(const short* __restrict__ A, const short* __restrict__ Bw,
             const float* __restrict__ bias, const float* __restrict__ aux,
             void* __restrict__ outv) {
  __shared__ short As[128 * 72];  // 128 rows x 64 cols, stride 72 (2-way conflict free)
  __shared__ short Bs[128 * 72];
  const int tid = threadIdx.x;
  const int lane = tid & 63, wave = tid >> 6;
  const int waveM = wave & 1, waveN = wave >> 1;
  const int l15 = lane & 15, quad = lane >> 4;
  const int row0 = blockIdx.x * 128, col0 = blockIdx.y * 128;

  const int sRow = tid >> 1, sCol = (tid & 1) * 32;
  const short* Ag = A + (long)(row0 + sRow) * K + sCol;
  const short* Bg = Bw + (long)(col0 + sRow) * K + sCol;
  short* Asw = As + sRow * 72 + sCol;
  short* Bsw = Bs + sRow * 72 + sCol;

  f32x4 acc[4][4];
#pragma unroll
  for (int i = 0; i < 4; i++)
#pragma unroll
    for (int j = 0; j < 4; j++) acc[i][j] = (f32x4){0.f, 0.f, 0.f, 0.f};

  const short* Ar = As + (waveM * 64 + l15) * 72 + quad * 8;
  const short* Br = Bs + (waveN * 64 + l15) * 72 + quad * 8;

  for (int k0 = 0; k0 < K; k0 += 64) {
    uint4 a0 = *(const uint4*)(Ag + 0);
    uint4 a1 = *(const uint4*)(Ag + 8);
    uint4 a2 = *(const uint4*)(Ag + 16);
    uint4 a3 = *(const uint4*)(Ag + 24);
    uint4 b0 = *(const uint4*)(Bg + 0);
    uint4 b1 = *(const uint4*)(Bg + 8);
    uint4 b2 = *(const uint4*)(Bg + 16);
    uint4 b3 = *(const uint4*)(Bg + 24);
    Ag += 64; Bg += 64;
    __syncthreads();
    *(uint4*)(Asw + 0) = a0;
    *(uint4*)(Asw + 8) = a1;
    *(uint4*)(Asw + 16) = a2;
    *(uint4*)(Asw + 24) = a3;
    *(uint4*)(Bsw + 0) = b0;
    *(uint4*)(Bsw + 8) = b1;
    *(uint4*)(Bsw + 16) = b2;
    *(uint4*)(Bsw + 24) = b3;
    __syncthreads();
#pragma unroll
    for (int ks = 0; ks < 64; ks += 32) {
      short8 af[4], bfv[4];
#pragma unroll
      for (int mt = 0; mt < 4; mt++)
        af[mt] = *(const short8*)(Ar + mt * 16 * 72 + ks);
#pragma unroll
      for (int nt = 0; nt < 4; nt++)
        bfv[nt] = *(const short8*)(Br + nt * 16 * 72 + ks);
#pragma unroll
      for (int mt = 0; mt < 4; mt++)
#pragma unroll
        for (int nt = 0; nt < 4; nt++)
          acc[mt][nt] = __builtin_amdgcn_mfma_f32_16x16x32_bf16(
              af[mt], bfv[nt], acc[mt][nt], 0, 0, 0);
    }
  }

  const int rowW = row0 + waveM * 64;
  const int colW = col0 + waveN * 64;
#pragma unroll
  for (int mt = 0; mt < 4; mt++) {
#pragma unroll
    for (int nt = 0; nt < 4; nt++) {
      const int col = colW + nt * 16 + l15;
      const float bv = bias[col];
#pragma unroll
      for (int reg = 0; reg < 4; reg++) {
        const int row = rowW + mt * 16 + quad * 4 + reg;
        float v = acc[mt][nt][reg] + bv;
        if constexpr (MODE == 0) {
          ((short*)outv)[(long)row * N + col] = f2bfbits(v);
        } else if constexpr (MODE == 1) {
          const int n = row & 63, wiB = row >> 6;
          const int wi = wiB & 63, bb = wiB >> 6;
          const int p = (((wi >> 3) << 3) + (n >> 3) + 4) & 63;
          const int q = (((wi & 7) << 3) + (n & 7) + 4) & 63;
          const long dst = ((long)bb * 4096 + p * 64 + q) * 512 + col;
          ((float*)outv)[dst] = v + aux[dst];
        } else if constexpr (MODE == 2) {
          const float g = 0.5f * v * (1.0f + erff(v * 0.70710678118654752f));
          ((short*)outv)[(long)row * N + col] = f2bfbits(g);
        } else {
          const long ix = (long)row * N + col;
          ((float*)outv)[ix] = v + aux[ix];
        }
      }
    }
  }
}

// ---------------- Windowed attention: one wave per (window, head) ----------
__global__ __launch_bounds__(256)
void attn(const short* __restrict__ qkv, const float* __restrict__ table,
          const int* __restrict__ idx, const float* __restrict__ mask,
          short* __restrict__ o) {
  __shared__ short P[4][64 * 72];
  const int lane = threadIdx.x & 63, wave = threadIdx.x >> 6;
  const int l15 = lane & 15, quad = lane >> 4;
  const int w = blockIdx.x;                 // 0..1023  (b*64 + wi)
  const int hh = blockIdx.y * 4 + wave;     // head 0..15
  const int wi = w & 63;
  const short* base = qkv + (long)w * 64 * 1536;

  // Q (A-layout) and K (B-layout) fragments: identical addressing pattern.
  short8 qf[4], kf[4];
#pragma unroll
  for (int mt = 0; mt < 4; mt++) {
    const int tq = mt * 16 + l15;
    qf[mt] = *(const short8*)(base + tq * 1536 + hh * 32 + quad * 8);
    kf[mt] = *(const short8*)(base + tq * 1536 + 512 + hh * 32 + quad * 8);
  }
  f32x4 S[4][4];
#pragma unroll
  for (int i = 0; i < 4; i++)
#pragma unroll
    for (int j = 0; j < 4; j++) S[i][j] = (f32x4){0.f, 0.f, 0.f, 0.f};
#pragma unroll
  for (int mt = 0; mt < 4; mt++)
#pragma unroll
    for (int nt = 0; nt < 4; nt++)
      S[mt][nt] = __builtin_amdgcn_mfma_f32_16x16x32_bf16(qf[mt], kf[nt], S[mt][nt], 0, 0, 0);

  // scale + rel-pos bias + shift mask + row softmax; P -> LDS (bf16, stride 72)
  short* pw = P[wave];
  const float scale = 0.17677669529663687f;  // 32^-0.5
#pragma unroll
  for (int mt = 0; mt < 4; mt++) {
#pragma unroll
    for (int reg = 0; reg < 4; reg++) {
      const int m = mt * 16 + quad * 4 + reg;
      float vals[4];
#pragma unroll
      for (int nt = 0; nt < 4; nt++) {
        const int n = nt * 16 + l15;
        float sv = S[mt][nt][reg] * scale;
        sv += table[idx[m * 64 + n] * 16 + hh];
        sv += mask[wi * 4096 + m * 64 + n];
        vals[nt] = sv;
      }
      float mx = fmaxf(fmaxf(vals[0], vals[1]), fmaxf(vals[2], vals[3]));
#pragma unroll
      for (int o_ = 1; o_ < 16; o_ <<= 1) mx = fmaxf(mx, __shfl_xor(mx, o_, 64));
      float e[4], sum = 0.f;
#pragma unroll
      for (int nt = 0; nt < 4; nt++) { e[nt] = __expf(vals[nt] - mx); sum += e[nt]; }
#pragma unroll
      for (int o_ = 1; o_ < 16; o_ <<= 1) sum += __shfl_xor(sum, o_, 64);
      const float inv = 1.0f / sum;
#pragma unroll
      for (int nt = 0; nt < 4; nt++)
        pw[m * 72 + nt * 16 + l15] = f2bfbits(e[nt] * inv);
    }
  }
  __syncthreads();

  // O = P @ V : P from LDS in A-layout, V gathered from global in B-layout.
  f32x4 O[4][2];
#pragma unroll
  for (int i = 0; i < 4; i++)
#pragma unroll
    for (int j = 0; j < 2; j++) O[i][j] = (f32x4){0.f, 0.f, 0.f, 0.f};
#pragma unroll
  for (int ks = 0; ks < 2; ks++) {
    short8 vf[2];
#pragma unroll
    for (int nt = 0; nt < 2; nt++) {
      short8 tv;
#pragma unroll
      for (int j = 0; j < 8; j++)
        tv[j] = base[(ks * 32 + quad * 8 + j) * 1536 + 1024 + hh * 32 + nt * 16 + l15];
      vf[nt] = tv;
    }
#pragma unroll
    for (int mt = 0; mt < 4; mt++) {
      short8 pf = *(const short8*)(pw + (mt * 16 + l15) * 72 + ks * 32 + quad * 8);
#pragma unroll
      for (int nt = 0; nt < 2; nt++)
        O[mt][nt] = __builtin_amdgcn_mfma_f32_16x16x32_bf16(pf, vf[nt], O[mt][nt], 0, 0, 0);
    }
  }
#pragma unroll
  for (int mt = 0; mt < 4; mt++)
#pragma unroll
    for (int nt = 0; nt < 2; nt++)
#pragma unroll
      for (int reg = 0; reg < 4; reg++) {
        const int t = mt * 16 + quad * 4 + reg;
        const int d = nt * 16 + l15;
        o[((long)w * 64 + t) * 512 + hh * 32 + d] = f2bfbits(O[mt][nt][reg]);
      }
}

extern "C" void kernel_launch(void* const* d_in, const int* in_sizes, int n_in,
                              void* d_out, int out_size, void* d_ws, size_t ws_size,
                              hipStream_t stream) {
  const float* x      = (const float*)d_in[0];
  const float* qkv_w  = (const float*)d_in[1];
  const float* qkv_b  = (const float*)d_in[2];
  const float* proj_w = (const float*)d_in[3];
  const float* proj_b = (const float*)d_in[4];
  const float* n1w    = (const float*)d_in[5];
  const float* n1b    = (const float*)d_in[6];
  const float* n2w    = (const float*)d_in[7];
  const float* n2b    = (const float*)d_in[8];
  const float* fc1_w  = (const float*)d_in[9];
  const float* fc1_b  = (const float*)d_in[10];
  const float* fc2_w  = (const float*)d_in[11];
  const float* fc2_b  = (const float*)d_in[12];
  const float* table  = (const float*)d_in[13];
  const int*   idx    = (const int*)d_in[14];
  const float* mask   = (const float*)d_in[15];

  char* ws = (char*)d_ws;
  // Workspace layout (bytes), peak 264 MiB:
  //   [0, 8Mi):       converted bf16 weights (persistent)
  //   [8Mi, 72Mi):    h (LN1 out) -> o (attn out) -> xn2 (LN2 out)   [bf16 64 MiB]
  //   [72Mi, 264Mi):  qkv (bf16 192 MiB) -> h2 chunk (bf16 128 MiB)
  // x2 (post-attn residual, fp32) lives in d_out and is overwritten by fc2.
  const long MB = 1048576L;
  short* wq  = (short*)(ws);
  short* wp  = wq + 786432;
  short* w1  = wp + 262144;
  short* w2  = w1 + 1048576;
  short* h   = (short*)(ws + 8 * MB);
  short* o   = h;                       // after h dead
  short* xn2 = h;                       // after o dead
  short* qkv = (short*)(ws + 72 * MB);
  short* h2c = qkv;                     // after qkv dead (32768 x 2048 bf16)
  float* out = (float*)d_out;           // also holds x2 (fp32) until fc2

  f2bf<<<768, 256, 0, stream>>>(qkv_w, wq, 786432);
  f2bf<<<256, 256, 0, stream>>>(proj_w, wp, 262144);
  f2bf<<<1024, 256, 0, stream>>>(fc1_w, w1, 1048576);
  f2bf<<<1024, 256, 0, stream>>>(fc2_w, w2, 1048576);

  ln1_win<<<16384, 256, 0, stream>>>(x, n1w, n1b, h);
  gemm_bt<0, 512, 1536><<<dim3(512, 12), 256, 0, stream>>>(h, wq, qkv_b, nullptr, qkv);
  attn<<<dim3(1024, 4), 256, 0, stream>>>(qkv, table, idx, mask, o);
  gemm_bt<1, 512, 512><<<dim3(512, 4), 256, 0, stream>>>(o, wp, proj_b, x, out);
  ln2_id<<<16384, 256, 0, stream>>>(out, n2w, n2b, xn2);
  // MLP in 2 row-chunks of 32768 (h2 chunk = 128 MiB fits the dead qkv region).
  for (int c = 0; c < 2; c++) {
    const long ro = (long)c * 32768;
    gemm_bt<2, 512, 2048><<<dim3(256, 16), 256, 0, stream>>>(
        xn2 + ro * 512, w1, fc1_b, nullptr, h2c);
    gemm_bt<3, 2048, 512><<<dim3(256, 4), 256, 0, stream>>>(
        h2c, w2, fc2_b, out + ro * 512, out + ro * 512);
  }
}

// Round 4
// 1225.941 us; speedup vs baseline: 1.0268x; 1.0268x over previous
//
#include <hip/hip_runtime.h>
#include <hip/hip_bf16.h>

typedef __attribute__((ext_vector_type(8))) short short8;
typedef __attribute__((ext_vector_type(4))) float f32x4;

__device__ __forceinline__ short f2bfbits(float f) {
  union { __hip_bfloat16 h; short s; } cvt;
  cvt.h = __float2bfloat16(f);
  return cvt.s;
}
__device__ __forceinline__ float bfbits2f(short bits) {
  union { unsigned int u; float f; } cvt;
  cvt.u = ((unsigned int)(unsigned short)bits) << 16;
  return cvt.f;
}

// Async global->LDS, 16 B per lane. LDS dest = wave-uniform base + lane*16.
__device__ __forceinline__ void gl_lds16(const short* g, short* l) {
  __builtin_amdgcn_global_load_lds(
      (__attribute__((address_space(1))) void*)(g),
      (__attribute__((address_space(3))) void*)(l), 16, 0, 0);
}

// ---------------- fp32 -> bf16 weight conversion ----------
__global__ __launch_bounds__(256)
void f2bf(const float* __restrict__ s, short* __restrict__ d, int n) {
  const int i = (blockIdx.x * 256 + threadIdx.x) * 4;
  if (i >= n) return;
  float4 v = *(const float4*)(s + i);
  short o[4] = {f2bfbits(v.x), f2bfbits(v.y), f2bfbits(v.z), f2bfbits(v.w)};
  *(uint2*)(d + i) = *(const uint2*)o;
}

// ---------------- combined rel-pos-bias + shift-mask table: bm[wi][h][m][n] bf16
__global__ __launch_bounds__(256)
void bm_build(const float* __restrict__ table, const int* __restrict__ idx,
              const float* __restrict__ mask, short* __restrict__ bm) {
  const int wi = blockIdx.x, hh = blockIdx.y;
  const int n = threadIdx.x & 63;
  const int m0 = (threadIdx.x >> 6) * 16;
#pragma unroll
  for (int mm = 0; mm < 16; mm++) {
    const int m = m0 + mm;
    const float t = table[idx[m * 64 + n] * 16 + hh];
    const float mk = mask[wi * 4096 + m * 64 + n];
    bm[((long)(wi * 16 + hh) * 64 + m) * 64 + n] = f2bfbits(t + mk);
  }
}

// ---------------- LN1 + roll(-4,-4) + window partition (fp32 in, bf16 out) --
__global__ __launch_bounds__(256)
void ln1_win(const float* __restrict__ x, const float* __restrict__ w,
             const float* __restrict__ b, short* __restrict__ h) {
  const int lane = threadIdx.x & 63;
  const int wv = threadIdx.x >> 6;
  const int t = blockIdx.x * 4 + wv;
  const int n = t & 63, wiB = t >> 6;
  const int wi = wiB & 63, bb = wiB >> 6;
  const int sr = (((wi >> 3) << 3) + (n >> 3) + 4) & 63;
  const int sc = (((wi & 7) << 3) + (n & 7) + 4) & 63;
  const float* xp = x + ((long)bb * 4096 + sr * 64 + sc) * 512 + lane * 8;
  float4 u0 = *(const float4*)(xp);
  float4 u1 = *(const float4*)(xp + 4);
  float v[8] = {u0.x, u0.y, u0.z, u0.w, u1.x, u1.y, u1.z, u1.w};
  float s = 0.f;
#pragma unroll
  for (int j = 0; j < 8; j++) s += v[j];
#pragma unroll
  for (int o = 1; o < 64; o <<= 1) s += __shfl_xor(s, o, 64);
  const float mean = s * (1.0f / 512.0f);
  float q = 0.f;
#pragma unroll
  for (int j = 0; j < 8; j++) { float d = v[j] - mean; q += d * d; }
#pragma unroll
  for (int o = 1; o < 64; o <<= 1) q += __shfl_xor(q, o, 64);
  const float rstd = rsqrtf(q * (1.0f / 512.0f) + 1e-5f);
  float4 w0 = *(const float4*)(w + lane * 8);
  float4 w1 = *(const float4*)(w + lane * 8 + 4);
  float4 b0 = *(const float4*)(b + lane * 8);
  float4 b1 = *(const float4*)(b + lane * 8 + 4);
  const float wv8[8] = {w0.x, w0.y, w0.z, w0.w, w1.x, w1.y, w1.z, w1.w};
  const float bv8[8] = {b0.x, b0.y, b0.z, b0.w, b1.x, b1.y, b1.z, b1.w};
  short outs[8];
#pragma unroll
  for (int j = 0; j < 8; j++)
    outs[j] = f2bfbits((v[j] - mean) * rstd * wv8[j] + bv8[j]);
  *(uint4*)(h + (long)t * 512 + lane * 8) = *(const uint4*)outs;
}

// ---------------- LN2 (identity layout, fp32 in, bf16 out) ----------------
__global__ __launch_bounds__(256)
void ln2_id(const float* __restrict__ x2, const float* __restrict__ w,
            const float* __restrict__ b, short* __restrict__ out) {
  const int lane = threadIdx.x & 63;
  const int wv = threadIdx.x >> 6;
  const long t = blockIdx.x * 4 + wv;
  const float* xp = x2 + t * 512 + lane * 8;
  float4 u0 = *(const float4*)(xp);
  float4 u1 = *(const float4*)(xp + 4);
  float v[8] = {u0.x, u0.y, u0.z, u0.w, u1.x, u1.y, u1.z, u1.w};
  float s = 0.f;
#pragma unroll
  for (int j = 0; j < 8; j++) s += v[j];
#pragma unroll
  for (int o = 1; o < 64; o <<= 1) s += __shfl_xor(s, o, 64);
  const float mean = s * (1.0f / 512.0f);
  float q = 0.f;
#pragma unroll
  for (int j = 0; j < 8; j++) { float d = v[j] - mean; q += d * d; }
#pragma unroll
  for (int o = 1; o < 64; o <<= 1) q += __shfl_xor(q, o, 64);
  const float rstd = rsqrtf(q * (1.0f / 512.0f) + 1e-5f);
  float4 w0 = *(const float4*)(w + lane * 8);
  float4 w1 = *(const float4*)(w + lane * 8 + 4);
  float4 b0 = *(const float4*)(b + lane * 8);
  float4 b1 = *(const float4*)(b + lane * 8 + 4);
  const float wv8[8] = {w0.x, w0.y, w0.z, w0.w, w1.x, w1.y, w1.z, w1.w};
  const float bv8[8] = {b0.x, b0.y, b0.z, b0.w, b1.x, b1.y, b1.z, b1.w};
  short outs[8];
#pragma unroll
  for (int j = 0; j < 8; j++)
    outs[j] = f2bfbits((v[j] - mean) * rstd * wv8[j] + bv8[j]);
  *(uint4*)(out + t * 512 + lane * 8) = *(const uint4*)outs;
}

// ---------------- Generic B^T GEMM: out[M,N] = A[M,K] @ Bw[N,K]^T + epilogue ----
// Staging via global_load_lds (width 16), unpadded [128][64] LDS tiles (m97 recipe).
// MODE 0: +bias -> Q/K to qk (stride 1024); V third transposed to out2 vT[w][h][d][tok]
// MODE 1: +bias, window-reverse + roll(+4) scatter, + residual aux (fp32) -> fp32
// MODE 2: +bias, exact GELU -> bf16
// MODE 3: +bias, + residual aux (fp32, row-major) -> fp32 (final out)
template <int MODE, int K, int N>
__global__ __launch_bounds__(256)
void gemm_bt(const short* __restrict__ A, const short* __restrict__ Bw,
             const float* __restrict__ bias, const float* __restrict__ aux,
             void* __restrict__ outv, short* __restrict__ out2) {
  __shared__ short As[128 * 64];
  __shared__ short Bs[128 * 64];
  const int tid = threadIdx.x;
  const int lane = tid & 63, wave = tid >> 6;
  const int waveM = wave & 1, waveN = wave >> 1;
  const int l15 = lane & 15, quad = lane >> 4;
  const int row0 = blockIdx.x * 128, col0 = blockIdx.y * 128;

  // staging: instr i covers rows i*32 + wave*8 + (lane>>3), cols (lane&7)*8
  const int sr = wave * 8 + (lane >> 3);
  const int sc = (lane & 7) * 8;
  const short* Ag = A + (long)(row0 + sr) * K + sc;
  const short* Bg = Bw + (long)(col0 + sr) * K + sc;
  short* Asw = As + wave * 512;  // lane*8 added by HW
  short* Bsw = Bs + wave * 512;

  f32x4 acc[4][4];
#pragma unroll
  for (int i = 0; i < 4; i++)
#pragma unroll
    for (int j = 0; j < 4; j++) acc[i][j] = (f32x4){0.f, 0.f, 0.f, 0.f};

  const short* Ar = As + (waveM * 64 + l15) * 64 + quad * 8;
  const short* Br = Bs + (waveN * 64 + l15) * 64 + quad * 8;

  for (int k0 = 0; k0 < K; k0 += 64) {
    __syncthreads();
#pragma unroll
    for (int i = 0; i < 4; i++) {
      gl_lds16(Ag + (long)i * 32 * K, Asw + i * 2048);
      gl_lds16(Bg + (long)i * 32 * K, Bsw + i * 2048);
    }
    Ag += 64; Bg += 64;
    __syncthreads();
#pragma unroll
    for (int ks = 0; ks < 64; ks += 32) {
      short8 af[4], bfv[4];
#pragma unroll
      for (int mt = 0; mt < 4; mt++)
        af[mt] = *(const short8*)(Ar + mt * 1024 + ks);
#pragma unroll
      for (int nt = 0; nt < 4; nt++)
        bfv[nt] = *(const short8*)(Br + nt * 1024 + ks);
#pragma unroll
      for (int mt = 0; mt < 4; mt++)
#pragma unroll
        for (int nt = 0; nt < 4; nt++)
          acc[mt][nt] = __builtin_amdgcn_mfma_f32_16x16x32_bf16(
              af[mt], bfv[nt], acc[mt][nt], 0, 0, 0);
    }
  }

  const int rowW = row0 + waveM * 64;
  const int colW = col0 + waveN * 64;
  if constexpr (MODE == 0) {
    if (col0 >= 1024) {
      // V third -> vT[((w*16+h)*32+d)*64 + tok], 4 consecutive toks packed per store
#pragma unroll
      for (int mt = 0; mt < 4; mt++) {
        const int rbase = rowW + mt * 16 + quad * 4;
        const int w = rbase >> 6, tokb = rbase & 63;
#pragma unroll
        for (int nt = 0; nt < 4; nt++) {
          const int col = colW + nt * 16 + l15;
          const float bv = bias[col];
          const int cg = col - 1024;
          const int head = cg >> 5, d = cg & 31;
          short pk[4];
#pragma unroll
          for (int reg = 0; reg < 4; reg++) pk[reg] = f2bfbits(acc[mt][nt][reg] + bv);
          *(uint2*)(out2 + ((long)(w * 16 + head) * 32 + d) * 64 + tokb) = *(const uint2*)pk;
        }
      }
    } else {
#pragma unroll
      for (int mt = 0; mt < 4; mt++)
#pragma unroll
        for (int nt = 0; nt < 4; nt++) {
          const int col = colW + nt * 16 + l15;
          const float bv = bias[col];
#pragma unroll
          for (int reg = 0; reg < 4; reg++) {
            const int row = rowW + mt * 16 + quad * 4 + reg;
            ((short*)outv)[(long)row * 1024 + col] = f2bfbits(acc[mt][nt][reg] + bv);
          }
        }
    }
  } else {
#pragma unroll
    for (int mt = 0; mt < 4; mt++) {
#pragma unroll
      for (int nt = 0; nt < 4; nt++) {
        const int col = colW + nt * 16 + l15;
        const float bv = bias[col];
#pragma unroll
        for (int reg = 0; reg < 4; reg++) {
          const int row = rowW + mt * 16 + quad * 4 + reg;
          float v = acc[mt][nt][reg] + bv;
          if constexpr (MODE == 1) {
            const int n = row & 63, wiB = row >> 6;
            const int wi = wiB & 63, bb = wiB >> 6;
            const int p = (((wi >> 3) << 3) + (n >> 3) + 4) & 63;
            const int q = (((wi & 7) << 3) + (n & 7) + 4) & 63;
            const long dst = ((long)bb * 4096 + p * 64 + q) * 512 + col;
            ((float*)outv)[dst] = v + aux[dst];
          } else if constexpr (MODE == 2) {
            const float g = 0.5f * v * (1.0f + erff(v * 0.70710678118654752f));
            ((short*)outv)[(long)row * N + col] = f2bfbits(g);
          } else {
            const long ix = (long)row * N + col;
            ((float*)outv)[ix] = v + aux[ix];
          }
        }
      }
    }
  }
}

// ---------------- Windowed attention: one wave per (window, head) ----------
__global__ __launch_bounds__(256)
void attn(const short* __restrict__ qk, const short* __restrict__ vT,
          const short* __restrict__ bm, short* __restrict__ o) {
  __shared__ short P[4][64 * 72];
  const int lane = threadIdx.x & 63, wave = threadIdx.x >> 6;
  const int l15 = lane & 15, quad = lane >> 4;
  const int w = blockIdx.x;                 // 0..1023  (b*64 + wi)
  const int hh = blockIdx.y * 4 + wave;     // head 0..15
  const int wi = w & 63;
  const short* base = qk + (long)w * 64 * 1024;

  short8 qf[4], kf[4];
#pragma unroll
  for (int mt = 0; mt < 4; mt++) {
    const int tq = mt * 16 + l15;
    qf[mt] = *(const short8*)(base + tq * 1024 + hh * 32 + quad * 8);
    kf[mt] = *(const short8*)(base + tq * 1024 + 512 + hh * 32 + quad * 8);
  }
  f32x4 S[4][4];
#pragma unroll
  for (int i = 0; i < 4; i++)
#pragma unroll
    for (int j = 0; j < 4; j++) S[i][j] = (f32x4){0.f, 0.f, 0.f, 0.f};
#pragma unroll
  for (int mt = 0; mt < 4; mt++)
#pragma unroll
    for (int nt = 0; nt < 4; nt++)
      S[mt][nt] = __builtin_amdgcn_mfma_f32_16x16x32_bf16(qf[mt], kf[nt], S[mt][nt], 0, 0, 0);

  // scale + combined bias/mask + row softmax; P -> LDS (bf16, stride 72)
  short* pw = P[wave];
  const short* bmp = bm + (long)(wi * 16 + hh) * 4096;
  const float scale = 0.17677669529663687f;  // 32^-0.5
#pragma unroll
  for (int mt = 0; mt < 4; mt++) {
#pragma unroll
    for (int reg = 0; reg < 4; reg++) {
      const int m = mt * 16 + quad * 4 + reg;
      float vals[4];
#pragma unroll
      for (int nt = 0; nt < 4; nt++)
        vals[nt] = S[mt][nt][reg] * scale + bfbits2f(bmp[m * 64 + nt * 16 + l15]);
      float mx = fmaxf(fmaxf(vals[0], vals[1]), fmaxf(vals[2], vals[3]));
#pragma unroll
      for (int o_ = 1; o_ < 16; o_ <<= 1) mx = fmaxf(mx, __shfl_xor(mx, o_, 64));
      float e[4], sum = 0.f;
#pragma unroll
      for (int nt = 0; nt < 4; nt++) { e[nt] = __expf(vals[nt] - mx); sum += e[nt]; }
#pragma unroll
      for (int o_ = 1; o_ < 16; o_ <<= 1) sum += __shfl_xor(sum, o_, 64);
      const float inv = 1.0f / sum;
#pragma unroll
      for (int nt = 0; nt < 4; nt++)
        pw[m * 72 + nt * 16 + l15] = f2bfbits(e[nt] * inv);
    }
  }
  __syncthreads();

  // O = P @ V : P from LDS (A-layout), V^T from global (B-layout, vector loads)
  const short* vbase = vT + (long)(w * 16 + hh) * 2048;
  f32x4 O[4][2];
#pragma unroll
  for (int i = 0; i < 4; i++)
#pragma unroll
    for (int j = 0; j < 2; j++) O[i][j] = (f32x4){0.f, 0.f, 0.f, 0.f};
#pragma unroll
  for (int ks = 0; ks < 2; ks++) {
    short8 vf[2];
#pragma unroll
    for (int nt = 0; nt < 2; nt++)
      vf[nt] = *(const short8*)(vbase + (nt * 16 + l15) * 64 + ks * 32 + quad * 8);
#pragma unroll
    for (int mt = 0; mt < 4; mt++) {
      short8 pf = *(const short8*)(pw + (mt * 16 + l15) * 72 + ks * 32 + quad * 8);
#pragma unroll
      for (int nt = 0; nt < 2; nt++)
        O[mt][nt] = __builtin_amdgcn_mfma_f32_16x16x32_bf16(pf, vf[nt], O[mt][nt], 0, 0, 0);
    }
  }
#pragma unroll
  for (int mt = 0; mt < 4; mt++)
#pragma unroll
    for (int nt = 0; nt < 2; nt++)
#pragma unroll
      for (int reg = 0; reg < 4; reg++) {
        const int t = mt * 16 + quad * 4 + reg;
        const int d = nt * 16 + l15;
        o[((long)w * 64 + t) * 512 + hh * 32 + d] = f2bfbits(O[mt][nt][reg]);
      }
}

extern "C" void kernel_launch(void* const* d_in, const int* in_sizes, int n_in,
                              void* d_out, int out_size, void* d_ws, size_t ws_size,
                              hipStream_t stream) {
  const float* x      = (const float*)d_in[0];
  const float* qkv_w  = (const float*)d_in[1];
  const float* qkv_b  = (const float*)d_in[2];
  const float* proj_w = (const float*)d_in[3];
  const float* proj_b = (const float*)d_in[4];
  const float* n1w    = (const float*)d_in[5];
  const float* n1b    = (const float*)d_in[6];
  const float* n2w    = (const float*)d_in[7];
  const float* n2b    = (const float*)d_in[8];
  const float* fc1_w  = (const float*)d_in[9];
  const float* fc1_b  = (const float*)d_in[10];
  const float* fc2_w  = (const float*)d_in[11];
  const float* fc2_b  = (const float*)d_in[12];
  const float* table  = (const float*)d_in[13];
  const int*   idx    = (const int*)d_in[14];
  const float* mask   = (const float*)d_in[15];

  char* ws = (char*)d_ws;
  // Workspace (peak 273 MiB):
  //   [0, 8Mi):    bf16 weights
  //   [8Mi,17Mi):  bm combined bias+mask (8.4 MB)
  //   [17Mi,81Mi): h (LN1) -> o (attn out) -> xn2 (LN2)   [bf16 64 MiB]
  //   [81Mi,209Mi): qk (bf16, Q|K stride 1024) -> h2 chunk (32768x2048 bf16)
  //   [209Mi,273Mi): vT (bf16, [1024][16][32][64])
  const long MB = 1048576L;
  short* wq  = (short*)(ws);
  short* wp  = wq + 786432;
  short* w1  = wp + 262144;
  short* w2  = w1 + 1048576;
  short* bm  = (short*)(ws + 8 * MB);
  short* h   = (short*)(ws + 17 * MB);
  short* o   = h;
  short* xn2 = h;
  short* qk  = (short*)(ws + 81 * MB);
  short* h2c = qk;
  short* vT  = (short*)(ws + 209 * MB);
  float* out = (float*)d_out;  // holds x2 (fp32) until fc2 overwrites

  f2bf<<<768, 256, 0, stream>>>(qkv_w, wq, 786432);
  f2bf<<<256, 256, 0, stream>>>(proj_w, wp, 262144);
  f2bf<<<1024, 256, 0, stream>>>(fc1_w, w1, 1048576);
  f2bf<<<1024, 256, 0, stream>>>(fc2_w, w2, 1048576);
  bm_build<<<dim3(64, 16), 256, 0, stream>>>(table, idx, mask, bm);

  ln1_win<<<16384, 256, 0, stream>>>(x, n1w, n1b, h);
  gemm_bt<0, 512, 1536><<<dim3(512, 12), 256, 0, stream>>>(h, wq, qkv_b, nullptr, qk, vT);
  attn<<<dim3(1024, 4), 256, 0, stream>>>(qk, vT, bm, o);
  gemm_bt<1, 512, 512><<<dim3(512, 4), 256, 0, stream>>>(o, wp, proj_b, x, out, nullptr);
  ln2_id<<<16384, 256, 0, stream>>>(out, n2w, n2b, xn2);
  for (int c = 0; c < 2; c++) {
    const long ro = (long)c * 32768;
    gemm_bt<2, 512, 2048><<<dim3(256, 16), 256, 0, stream>>>(
        xn2 + ro * 512, w1, fc1_b, nullptr, h2c, nullptr);
    gemm_bt<3, 2048, 512><<<dim3(256, 4), 256, 0, stream>>>(
        h2c, w2, fc2_b, out + ro * 512, out + ro * 512, nullptr);
  }
}